// Round 1
// baseline (1332.830 us; speedup 1.0000x reference)
//
#include <hip/hip_runtime.h>
#include <math.h>

// Problem constants
#define B_DIM 8
#define T_DIM 2048
#define C_DIM 1024
#define HS_DIM 128
#define VD 256
#define M_DIM (B_DIM * T_DIM)            // 16384 rows
#define QK_TERM (M_DIM * HS_DIM)         // 2,097,152 floats per (q|k) term
#define SCALE 0.088388347648318447f      // 1/sqrt(128)
#define LOG_THETA 9.210340371976184f     // ln(10000)

// ---------- helpers: bf16 packing (RNE) ----------
__device__ __forceinline__ unsigned int bf16_rne(float f) {
    unsigned int u = __float_as_uint(f);
    return (u + 0x7fffu + ((u >> 16) & 1u)) >> 16;
}
__device__ __forceinline__ unsigned int pack_bf2(float lo, float hi) {
    return bf16_rne(lo) | (bf16_rne(hi) << 16);
}
__device__ __forceinline__ float bflo(unsigned int u) { return __uint_as_float(u << 16); }
__device__ __forceinline__ float bfhi(unsigned int u) { return __uint_as_float(u & 0xffff0000u); }

// ---------- kernel 1: lambda coefficients ----------
// c0 = +lam0 = e0 + lam_init ; c1 = -lam1 = -(e1 - e0 + lam_init)
__global__ void lam_kernel(const float* __restrict__ lq, const float* __restrict__ lk,
                           const int* __restrict__ lidx, float* __restrict__ lam_out) {
    int t = threadIdx.x; // 64 threads = 1 wave
    float s0 = expf(lq[t] * lk[t]) + expf(lq[t + 64] * lk[t + 64]);
    float s1 = expf(lq[128 + t] * lk[128 + t]) + expf(lq[192 + t] * lk[192 + t]);
    #pragma unroll
    for (int off = 32; off > 0; off >>= 1) {
        s0 += __shfl_down(s0, off);
        s1 += __shfl_down(s1, off);
    }
    if (t == 0) {
        float e0 = s0 * (1.0f / 128.0f);
        float e1 = s1 * (1.0f / 128.0f);
        float li = 0.8f - 0.6f * expf(-0.3f * ((float)lidx[0] - 1.0f));
        lam_out[0] = e0 + li;
        lam_out[1] = -(e1 - e0 + li);
    }
}

// ---------- kernel 2: fused QKV projection + RoPE ----------
// X[16384][1024] @ W[1024][768] ; cols 0-127 Q0, 128-255 Q1, 256-383 K0,
// 384-511 K1, 512-767 V. RoPE applied to Q/K on store.
// BM=128, BN=128, BK=16, 256 threads, 8x8 per thread (split 4+4 rows/cols).
__global__ __launch_bounds__(256) void proj_kernel(
    const float* __restrict__ x, const float* __restrict__ Wq,
    const float* __restrict__ Wk, const float* __restrict__ Wv,
    float* __restrict__ qo, float* __restrict__ ko, float* __restrict__ vo) {
    __shared__ float XsT[16][132];  // [k][row], padded
    __shared__ float Ws[16][132];   // [k][col], padded

    const int t = threadIdx.x;
    const int m0 = blockIdx.x * 128;
    const int n0 = blockIdx.y * 128;
    const int ty = t >> 4, tx = t & 15;

    float acc[8][8];
    #pragma unroll
    for (int r = 0; r < 8; ++r)
        #pragma unroll
        for (int c = 0; c < 8; ++c) acc[r][c] = 0.f;

    // resolve W source pointers once (column assignment is k-invariant)
    const float* wbase[2];
    int wld[2];
    #pragma unroll
    for (int rep = 0; rep < 2; ++rep) {
        int idx4 = t + rep * 256;
        int cseg = idx4 & 31;
        int gc = n0 + cseg * 4;
        if (gc < 256)      { wbase[rep] = Wq + (size_t)(gc >> 7) * (C_DIM * HS_DIM) + (gc & 127); wld[rep] = 128; }
        else if (gc < 512) { wbase[rep] = Wk + (size_t)((gc - 256) >> 7) * (C_DIM * HS_DIM) + (gc & 127); wld[rep] = 128; }
        else               { wbase[rep] = Wv + (gc - 512); wld[rep] = 256; }
    }

    for (int k0 = 0; k0 < C_DIM; k0 += 16) {
        // stage X tile transposed: 128 rows x 16 k
        #pragma unroll
        for (int rep = 0; rep < 2; ++rep) {
            int idx4 = t + rep * 256;
            int row = idx4 >> 2;
            int seg = idx4 & 3;
            float4 g = *(const float4*)(x + (size_t)(m0 + row) * C_DIM + k0 + seg * 4);
            XsT[seg * 4 + 0][row] = g.x;
            XsT[seg * 4 + 1][row] = g.y;
            XsT[seg * 4 + 2][row] = g.z;
            XsT[seg * 4 + 3][row] = g.w;
        }
        // stage W tile: 16 k x 128 cols
        #pragma unroll
        for (int rep = 0; rep < 2; ++rep) {
            int idx4 = t + rep * 256;
            int kk = idx4 >> 5;
            int cseg = idx4 & 31;
            float4 g = *(const float4*)(wbase[rep] + (size_t)(k0 + kk) * wld[rep]);
            *(float4*)&Ws[kk][cseg * 4] = g;
        }
        __syncthreads();
        #pragma unroll
        for (int kk = 0; kk < 16; ++kk) {
            float a[8], bb[8];
            *(float4*)&a[0]  = *(const float4*)&XsT[kk][ty * 4];
            *(float4*)&a[4]  = *(const float4*)&XsT[kk][64 + ty * 4];
            *(float4*)&bb[0] = *(const float4*)&Ws[kk][tx * 4];
            *(float4*)&bb[4] = *(const float4*)&Ws[kk][64 + tx * 4];
            #pragma unroll
            for (int r = 0; r < 8; ++r)
                #pragma unroll
                for (int c = 0; c < 8; ++c)
                    acc[r][c] = fmaf(a[r], bb[c], acc[r][c]);
        }
        __syncthreads();
    }

    // epilogue
    const int segid = n0 >> 7; // 0..5 (uniform per block)
    // precompute RoPE freqs for this thread's 2 col-halves x 2 pairs
    float freqs[2][2];
    if (segid < 4) {
        #pragma unroll
        for (int half = 0; half < 2; ++half) {
            int d0 = ((half ? 64 + tx * 4 : tx * 4)) & 127; // n0 aligned to 128
            #pragma unroll
            for (int p = 0; p < 2; ++p)
                freqs[half][p] = __expf((float)(d0 + 2 * p) * (-LOG_THETA / 128.f));
        }
    }
    #pragma unroll
    for (int r = 0; r < 8; ++r) {
        const int grow = m0 + ((r < 4) ? (ty * 4 + r) : (64 + ty * 4 + (r - 4)));
        const int trow = grow & (T_DIM - 1);
        #pragma unroll
        for (int half = 0; half < 2; ++half) {
            const int cbase = half ? (64 + tx * 4) : (tx * 4);
            const int gcol = n0 + cbase;
            float v0 = acc[r][half * 4 + 0];
            float v1 = acc[r][half * 4 + 1];
            float v2 = acc[r][half * 4 + 2];
            float v3 = acc[r][half * 4 + 3];
            if (segid < 4) {
                const int d0 = gcol & 127;
                float* dst = ((segid < 2) ? qo : ko) + (size_t)(segid & 1) * QK_TERM + (size_t)grow * HS_DIM;
                #pragma unroll
                for (int p = 0; p < 2; ++p) {
                    const float ang = (float)trow * freqs[half][p];
                    float sn_, cs_;
                    __sincosf(ang, &sn_, &cs_);
                    const float xr = (p == 0) ? v0 : v2;
                    const float xi = (p == 0) ? v1 : v3;
                    float2 o2 = make_float2(xr * cs_ - xi * sn_, xr * sn_ + xi * cs_);
                    *(float2*)&dst[d0 + 2 * p] = o2;
                }
            } else {
                float* dst = vo + (size_t)grow * VD + (gcol - 512);
                *(float4*)dst = make_float4(v0, v1, v2, v3);
            }
        }
    }
}

// ---------- kernel 3: dual-term causal flash attention ----------
// Block: 256 threads, TQ=16 q rows for one b, TK=32 k rows per tile.
// out = c0 * softmax(Q0 K0^T)/l0 @ V + c1 * softmax(Q1 K1^T)/l1 @ V
__global__ __launch_bounds__(256) void attn_kernel(
    const float* __restrict__ qg, const float* __restrict__ kg,
    const float* __restrict__ vg, const float* __restrict__ lam,
    float* __restrict__ outp) {
    __shared__ unsigned int Qs[2][16][66]; // bf16x2 pairs, padded stride
    __shared__ unsigned int Ks[2][32][66];
    __shared__ float Vs[32][256];
    __shared__ float Sm[2][16][33];        // probabilities, padded
    __shared__ float rowa[2][16];          // per-tile alpha
    __shared__ float rowl[2][16];          // final l

    const int t = threadIdx.x;
    const int b = blockIdx.y;
    const int qt = (int)(gridDim.x - 1) - (int)blockIdx.x; // heavy blocks first
    const int q0 = qt * 16;

    // score-phase mapping: (term, row, jj-group-of-4)
    const int sn = t >> 7;
    const int si = (t >> 3) & 15;
    const int sg = t & 7;
    // PV-phase mapping: (row, interleaved dim)
    const int ci = t >> 4;
    const int cc = t & 15;

    float o0[16], o1[16];
    #pragma unroll
    for (int e = 0; e < 16; ++e) { o0[e] = 0.f; o1[e] = 0.f; }
    float m_run = -1e30f, l_run = 0.f;

    // stage Q tile once: 2 x 16 x 128 floats -> bf16 pairs
    #pragma unroll
    for (int rep = 0; rep < 4; ++rep) {
        int idx4 = t + rep * 256;       // 0..1023
        int n = idx4 >> 9;
        int r = idx4 & 511;
        int i = r >> 5;
        int d0 = (r & 31) * 4;
        const float4 g = *(const float4*)(qg + (size_t)n * QK_TERM + (size_t)(b * T_DIM + q0 + i) * HS_DIM + d0);
        Qs[n][i][(d0 >> 1) + 0] = pack_bf2(g.x, g.y);
        Qs[n][i][(d0 >> 1) + 1] = pack_bf2(g.z, g.w);
    }

    const int ntiles = (q0 + 16 + 31) >> 5;
    for (int it = 0; it < ntiles; ++it) {
        const int s0 = it * 32;
        // stage K tile: 2 x 32 x 128 floats
        #pragma unroll
        for (int rep = 0; rep < 8; ++rep) {
            int idx4 = t + rep * 256;   // 0..2047
            int n = idx4 >> 10;
            int r = idx4 & 1023;
            int j = r >> 5;
            int d0 = (r & 31) * 4;
            const float4 g = *(const float4*)(kg + (size_t)n * QK_TERM + (size_t)(b * T_DIM + s0 + j) * HS_DIM + d0);
            Ks[n][j][(d0 >> 1) + 0] = pack_bf2(g.x, g.y);
            Ks[n][j][(d0 >> 1) + 1] = pack_bf2(g.z, g.w);
        }
        // stage V tile: 32 x 256 floats (fp32)
        #pragma unroll
        for (int rep = 0; rep < 8; ++rep) {
            int idx4 = t + rep * 256;   // 0..2047
            int j = idx4 >> 6;
            int d0 = (idx4 & 63) * 4;
            *(float4*)&Vs[j][d0] = *(const float4*)(vg + (size_t)(b * T_DIM + s0 + j) * VD + d0);
        }
        __syncthreads();

        // scores + online softmax (each thread: 4 jj for one (n,row))
        {
            float acc0 = 0.f, acc1 = 0.f, acc2 = 0.f, acc3 = 0.f;
            const int jj0 = sg * 4;
            #pragma unroll 8
            for (int p = 0; p < 64; ++p) {
                const unsigned int uq = Qs[sn][si][p];
                const float qlo = bflo(uq), qhi = bfhi(uq);
                unsigned int uk;
                uk = Ks[sn][jj0 + 0][p]; acc0 = fmaf(qlo, bflo(uk), acc0); acc0 = fmaf(qhi, bfhi(uk), acc0);
                uk = Ks[sn][jj0 + 1][p]; acc1 = fmaf(qlo, bflo(uk), acc1); acc1 = fmaf(qhi, bfhi(uk), acc1);
                uk = Ks[sn][jj0 + 2][p]; acc2 = fmaf(qlo, bflo(uk), acc2); acc2 = fmaf(qhi, bfhi(uk), acc2);
                uk = Ks[sn][jj0 + 3][p]; acc3 = fmaf(qlo, bflo(uk), acc3); acc3 = fmaf(qhi, bfhi(uk), acc3);
            }
            float s[4];
            s[0] = acc0 * SCALE; s[1] = acc1 * SCALE; s[2] = acc2 * SCALE; s[3] = acc3 * SCALE;
            float tmax = -1e30f;
            #pragma unroll
            for (int e = 0; e < 4; ++e) {
                const bool ok = (s0 + jj0 + e) <= (q0 + si);
                s[e] = ok ? s[e] : -1e30f;
                tmax = fmaxf(tmax, s[e]);
            }
            #pragma unroll
            for (int off = 1; off < 8; off <<= 1) tmax = fmaxf(tmax, __shfl_xor(tmax, off));
            const float mnew = fmaxf(m_run, tmax);
            const float alpha = __expf(m_run - mnew);
            float psum = 0.f;
            #pragma unroll
            for (int e = 0; e < 4; ++e) {
                const float p = __expf(s[e] - mnew);
                Sm[sn][si][jj0 + e] = p;
                psum += p;
            }
            #pragma unroll
            for (int off = 1; off < 8; off <<= 1) psum += __shfl_xor(psum, off);
            l_run = l_run * alpha + psum;
            m_run = mnew;
            if (sg == 0) rowa[sn][si] = alpha;
        }
        __syncthreads();

        // PV accumulate (each thread: one row, 16 interleaved dims, both terms)
        {
            const float a0 = rowa[0][ci];
            const float a1 = rowa[1][ci];
            #pragma unroll
            for (int e = 0; e < 16; ++e) { o0[e] *= a0; o1[e] *= a1; }
            #pragma unroll 4
            for (int jj = 0; jj < 32; ++jj) {
                const float p0 = Sm[0][ci][jj];
                const float p1 = Sm[1][ci][jj];
                #pragma unroll
                for (int e = 0; e < 16; ++e) {
                    const float v = Vs[jj][cc + (e << 4)];
                    o0[e] = fmaf(p0, v, o0[e]);
                    o1[e] = fmaf(p1, v, o1[e]);
                }
            }
        }
        __syncthreads();
    }

    if (sg == 0) rowl[sn][si] = l_run;
    __syncthreads();

    const float c0 = lam[0], c1 = lam[1];
    const float il0 = 1.f / rowl[0][ci];
    const float il1 = 1.f / rowl[1][ci];
    float* orow = outp + (size_t)(b * T_DIM + q0 + ci) * VD;
    #pragma unroll
    for (int e = 0; e < 16; ++e)
        orow[cc + (e << 4)] = c0 * o0[e] * il0 + c1 * o1[e] * il1;
}

extern "C" void kernel_launch(void* const* d_in, const int* in_sizes, int n_in,
                              void* d_out, int out_size, void* d_ws, size_t ws_size,
                              hipStream_t stream) {
    const float* x  = (const float*)d_in[0];
    const float* Wq = (const float*)d_in[1];
    const float* Wk = (const float*)d_in[2];
    const float* Wv = (const float*)d_in[3];
    const float* lq = (const float*)d_in[4];
    const float* lk = (const float*)d_in[5];
    const int* lidx = (const int*)d_in[6];

    float* ws = (float*)d_ws;
    float* qb   = ws;                          // [2][M][128]
    float* kb   = ws + 2 * (size_t)QK_TERM;    // [2][M][128]
    float* vb   = ws + 4 * (size_t)QK_TERM;    // [M][256] (= 2*QK_TERM floats)
    float* lamb = ws + 6 * (size_t)QK_TERM;    // [2]
    (void)ws_size; (void)in_sizes; (void)n_in; (void)out_size;

    lam_kernel<<<dim3(1), dim3(64), 0, stream>>>(lq, lk, lidx, lamb);
    proj_kernel<<<dim3(128, 6), dim3(256), 0, stream>>>(x, Wq, Wk, Wv, qb, kb, vb);
    attn_kernel<<<dim3(128, 8), dim3(256), 0, stream>>>(qb, kb, vb, lamb, (float*)d_out);
}

// Round 2
// 488.949 us; speedup vs baseline: 2.7259x; 2.7259x over previous
//
#include <hip/hip_runtime.h>
#include <math.h>

// Problem constants
#define B_DIM 8
#define T_DIM 2048
#define C_DIM 1024
#define HS_DIM 128
#define VD 256
#define M_DIM (B_DIM * T_DIM)            // 16384 rows
#define QK_ELEMS (M_DIM * HS_DIM)        // 2,097,152 elems per (q|k) term
#define SCALE 0.088388347648318447f      // 1/sqrt(128)
#define LOG_THETA 9.210340371976184f     // ln(10000)

typedef short s8v  __attribute__((ext_vector_type(8)));   // 8 bf16 (4 VGPRs)
typedef float f32x4 __attribute__((ext_vector_type(4)));

// ---------- helpers: bf16 packing (RNE) ----------
__device__ __forceinline__ unsigned int bf16_rne(float f) {
    unsigned int u = __float_as_uint(f);
    return (u + 0x7fffu + ((u >> 16) & 1u)) >> 16;
}
__device__ __forceinline__ unsigned int pack_bf2(float lo, float hi) {
    return bf16_rne(lo) | (bf16_rne(hi) << 16);
}

// ---------- kernel 1: lambda coefficients ----------
__global__ void lam_kernel(const float* __restrict__ lq, const float* __restrict__ lk,
                           const int* __restrict__ lidx, float* __restrict__ lam_out) {
    int t = threadIdx.x; // 64 threads = 1 wave
    float s0 = expf(lq[t] * lk[t]) + expf(lq[t + 64] * lk[t + 64]);
    float s1 = expf(lq[128 + t] * lk[128 + t]) + expf(lq[192 + t] * lk[192 + t]);
    #pragma unroll
    for (int off = 32; off > 0; off >>= 1) {
        s0 += __shfl_down(s0, off);
        s1 += __shfl_down(s1, off);
    }
    if (t == 0) {
        float e0 = s0 * (1.0f / 128.0f);
        float e1 = s1 * (1.0f / 128.0f);
        float li = 0.8f - 0.6f * expf(-0.3f * ((float)lidx[0] - 1.0f));
        lam_out[0] = e0 + li;            // +lam0
        lam_out[1] = -(e1 - e0 + li);    // -lam1
    }
}

// ---------- kernel 2: fused QKV projection + RoPE (fp32 core, bf16 outputs) ----
// X[16384][1024] @ W[1024][768]; cols 0-127 Q0, 128-255 Q1, 256-383 K0,
// 384-511 K1, 512-767 V. Q/K: RoPE then bf16 [term][b][t][128].
// V: bf16 TRANSPOSED vT[b][256][2048] (for contiguous PV B-frags in attn).
__global__ __launch_bounds__(256) void proj_kernel(
    const float* __restrict__ x, const float* __restrict__ Wq,
    const float* __restrict__ Wk, const float* __restrict__ Wv,
    unsigned short* __restrict__ qo, unsigned short* __restrict__ ko,
    unsigned short* __restrict__ vo) {
    __shared__ float XsT[16][132];  // [k][row], padded
    __shared__ float Ws[16][132];   // [k][col], padded

    const int t = threadIdx.x;
    const int m0 = blockIdx.x * 128;
    const int n0 = blockIdx.y * 128;
    const int ty = t >> 4, tx = t & 15;

    float acc[8][8];
    #pragma unroll
    for (int r = 0; r < 8; ++r)
        #pragma unroll
        for (int c = 0; c < 8; ++c) acc[r][c] = 0.f;

    const float* wbase[2];
    int wld[2];
    #pragma unroll
    for (int rep = 0; rep < 2; ++rep) {
        int idx4 = t + rep * 256;
        int cseg = idx4 & 31;
        int gc = n0 + cseg * 4;
        if (gc < 256)      { wbase[rep] = Wq + (size_t)(gc >> 7) * (C_DIM * HS_DIM) + (gc & 127); wld[rep] = 128; }
        else if (gc < 512) { wbase[rep] = Wk + (size_t)((gc - 256) >> 7) * (C_DIM * HS_DIM) + (gc & 127); wld[rep] = 128; }
        else               { wbase[rep] = Wv + (gc - 512); wld[rep] = 256; }
    }

    for (int k0 = 0; k0 < C_DIM; k0 += 16) {
        #pragma unroll
        for (int rep = 0; rep < 2; ++rep) {
            int idx4 = t + rep * 256;
            int row = idx4 >> 2;
            int seg = idx4 & 3;
            float4 g = *(const float4*)(x + (size_t)(m0 + row) * C_DIM + k0 + seg * 4);
            XsT[seg * 4 + 0][row] = g.x;
            XsT[seg * 4 + 1][row] = g.y;
            XsT[seg * 4 + 2][row] = g.z;
            XsT[seg * 4 + 3][row] = g.w;
        }
        #pragma unroll
        for (int rep = 0; rep < 2; ++rep) {
            int idx4 = t + rep * 256;
            int kk = idx4 >> 5;
            int cseg = idx4 & 31;
            float4 g = *(const float4*)(wbase[rep] + (size_t)(k0 + kk) * wld[rep]);
            *(float4*)&Ws[kk][cseg * 4] = g;
        }
        __syncthreads();
        #pragma unroll
        for (int kk = 0; kk < 16; ++kk) {
            float a[8], bb[8];
            *(float4*)&a[0]  = *(const float4*)&XsT[kk][ty * 4];
            *(float4*)&a[4]  = *(const float4*)&XsT[kk][64 + ty * 4];
            *(float4*)&bb[0] = *(const float4*)&Ws[kk][tx * 4];
            *(float4*)&bb[4] = *(const float4*)&Ws[kk][64 + tx * 4];
            #pragma unroll
            for (int r = 0; r < 8; ++r)
                #pragma unroll
                for (int c = 0; c < 8; ++c)
                    acc[r][c] = fmaf(a[r], bb[c], acc[r][c]);
        }
        __syncthreads();
    }

    const int segid = n0 >> 7; // 0..5 (uniform per block)
    if (segid >= 4) {
        // V segment: write bf16 transposed vT[b][dim][token], token pairs packed
        const int bq = m0 >> 11;
        const int tbase = m0 & 2047;             // multiple of 128 (even)
        unsigned int* vT32 = (unsigned int*)vo;
        #pragma unroll
        for (int half = 0; half < 2; ++half) {
            #pragma unroll
            for (int c = 0; c < 4; ++c) {
                const int d = (n0 - 512) + half * 64 + tx * 4 + c;
                const size_t rowbase = ((size_t)(bq * 256 + d)) * (T_DIM / 2); // u32 units
                #pragma unroll
                for (int m = 0; m < 4; ++m) {
                    const int r0 = 2 * m, r1 = 2 * m + 1;
                    const int tok = (m < 2) ? (tbase + ty * 4 + 2 * m)
                                            : (tbase + 64 + ty * 4 + (2 * m - 4));
                    vT32[rowbase + (tok >> 1)] = pack_bf2(acc[r0][half * 4 + c],
                                                          acc[r1][half * 4 + c]);
                }
            }
        }
    } else {
        // Q/K segments: RoPE then bf16 row-major [term][token][128]
        float freqs[2][2];
        #pragma unroll
        for (int half = 0; half < 2; ++half) {
            int d0 = (half ? 64 + tx * 4 : tx * 4) & 127;
            #pragma unroll
            for (int p = 0; p < 2; ++p)
                freqs[half][p] = __expf((float)(d0 + 2 * p) * (-LOG_THETA / 128.f));
        }
        #pragma unroll
        for (int r = 0; r < 8; ++r) {
            const int grow = m0 + ((r < 4) ? (ty * 4 + r) : (64 + ty * 4 + (r - 4)));
            const int trow = grow & (T_DIM - 1);
            unsigned short* dst = ((segid < 2) ? qo : ko)
                                  + (size_t)(segid & 1) * QK_ELEMS + (size_t)grow * HS_DIM;
            unsigned int* dst32 = (unsigned int*)dst;
            #pragma unroll
            for (int half = 0; half < 2; ++half) {
                const int d0 = (half ? 64 + tx * 4 : tx * 4);
                float v0 = acc[r][half * 4 + 0];
                float v1 = acc[r][half * 4 + 1];
                float v2 = acc[r][half * 4 + 2];
                float v3 = acc[r][half * 4 + 3];
                unsigned int u[2];
                #pragma unroll
                for (int p = 0; p < 2; ++p) {
                    const float ang = (float)trow * freqs[half][p];
                    float sn_, cs_;
                    __sincosf(ang, &sn_, &cs_);
                    const float xr = (p == 0) ? v0 : v2;
                    const float xi = (p == 0) ? v1 : v3;
                    u[p] = pack_bf2(xr * cs_ - xi * sn_, xr * sn_ + xi * cs_);
                }
                *(uint2*)&dst32[d0 >> 1] = make_uint2(u[0], u[1]);
            }
        }
    }
}

// ---------- kernel 3: dual-term causal attention, bf16 MFMA ----------
// Grid: 256 blocks (b = id&7 for XCD-L2 pinning, qt = id>>3 in [0,32)).
// Each block: two complementary 32-query strips (qt, 63-qt) -> 65 K-tile
// iterations per block, uniform work, 1 block/CU.
// Waves: w = (term = w&1, qhalf = w>>1). Fixed-max softmax (scores << 80).
#define KROWSTR 136   // K LDS row stride (bf16), +8 pad
#define VROWSTR 40    // Vt LDS row stride
#define PROWSTR 40    // P LDS row stride
#define OROWSTR 268   // O LDS row stride (fp32)
#define SM_K_OFF 0
#define SM_V_OFF 17408
#define SM_P_OFF 37888
#define SM_TOTAL 43008

__global__ __launch_bounds__(256) void attn_kernel(
    const unsigned short* __restrict__ qg, const unsigned short* __restrict__ kg,
    const unsigned short* __restrict__ vg, const float* __restrict__ lam,
    float* __restrict__ outp) {
    __shared__ __align__(16) unsigned char smem[SM_TOTAL];
    unsigned short* KsP = (unsigned short*)(smem + SM_K_OFF);  // [2][32][136]
    unsigned short* VtP = (unsigned short*)(smem + SM_V_OFF);  // [256][40]
    unsigned short* PsP = (unsigned short*)(smem + SM_P_OFF);  // [4][16][40]
    float* OlP = (float*)smem;                                 // [2][16][268] overlays K+V

    const int t = threadIdx.x;
    const int id = blockIdx.x;
    const int b = id & 7;          // batch pinned to XCD (round-robin heuristic)
    const int qt = id >> 3;        // 0..31
    const int w = t >> 6;
    const int lane = t & 63;
    const int quad = lane >> 4;
    const int l15 = lane & 15;
    const int n_term = w & 1;
    const int qh = w >> 1;

    const float cn = lam[n_term];  // lam[1] already carries the minus sign

    #pragma unroll
    for (int sidx = 0; sidx < 2; ++sidx) {
        const int qte = sidx ? (63 - qt) : qt;
        const int q0 = qte * 32;
        const int nt = qte + 1;

        // Q A-frags for this wave's 16 rows, its term, all K (once per strip)
        const unsigned short* qrow = qg
            + ((size_t)(n_term * B_DIM + b) * T_DIM + q0 + 16 * qh + l15) * HS_DIM;
        s8v qa[4];
        #pragma unroll
        for (int kk = 0; kk < 4; ++kk)
            qa[kk] = *(const s8v*)(qrow + kk * 32 + quad * 8);

        f32x4 o[16];
        #pragma unroll
        for (int d = 0; d < 16; ++d) o[d] = (f32x4){0.f, 0.f, 0.f, 0.f};
        float l_acc[4] = {0.f, 0.f, 0.f, 0.f};

        for (int it = 0; it < nt; ++it) {
            const int s0 = it * 32;
            // ---- stage K (2x32x128) and Vt (256x32) tiles, bf16 ----
            #pragma unroll
            for (int rep = 0; rep < 4; ++rep) {
                int idx = t + rep * 256;          // 0..1023 uint4s
                int n = idx >> 9, rem = idx & 511;
                int r = rem >> 4, seg = rem & 15;
                const uint4 g = *(const uint4*)(kg
                    + ((size_t)(n * B_DIM + b) * T_DIM + s0 + r) * HS_DIM + seg * 8);
                *(uint4*)&KsP[(n * 32 + r) * KROWSTR + seg * 8] = g;
            }
            #pragma unroll
            for (int rep = 0; rep < 4; ++rep) {
                int idx = t + rep * 256;          // 0..1023 uint4s
                int row = idx >> 2, seg = idx & 3;
                const uint4 g = *(const uint4*)(vg
                    + ((size_t)(b * VD + row) * T_DIM + s0) + seg * 8);
                *(uint4*)&VtP[row * VROWSTR + seg * 8] = g;
            }
            __syncthreads();

            // ---- scores: S[16q x 32k] for (term, qh), then exp -> P (bf16 LDS) ----
            #pragma unroll
            for (int ks = 0; ks < 2; ++ks) {
                f32x4 sc = (f32x4){0.f, 0.f, 0.f, 0.f};
                #pragma unroll
                for (int kk = 0; kk < 4; ++kk) {
                    s8v kf = *(const s8v*)&KsP[(n_term * 32 + ks * 16 + l15) * KROWSTR
                                               + kk * 32 + quad * 8];
                    sc = __builtin_amdgcn_mfma_f32_16x16x32_bf16(qa[kk], kf, sc, 0, 0, 0);
                }
                const int key = s0 + ks * 16 + l15;
                #pragma unroll
                for (int e = 0; e < 4; ++e) {
                    const int qrow_g = q0 + 16 * qh + quad * 4 + e;
                    const float p = (key <= qrow_g) ? __expf(sc[e] * SCALE) : 0.f;
                    l_acc[e] += p;
                    PsP[(w * 16 + quad * 4 + e) * PROWSTR + ks * 16 + l15] =
                        (unsigned short)bf16_rne(p);
                }
            }
            asm volatile("" ::: "memory");  // keep P-writes before A-frag read

            // ---- PV: O[16q x 256d] += P[16x32] @ V[32x256] (same wave's P) ----
            const s8v pa = *(const s8v*)&PsP[(w * 16 + l15) * PROWSTR + quad * 8];
            #pragma unroll
            for (int d = 0; d < 16; ++d) {
                s8v vb = *(const s8v*)&VtP[(d * 16 + l15) * VROWSTR + quad * 8];
                o[d] = __builtin_amdgcn_mfma_f32_16x16x32_bf16(pa, vb, o[d], 0, 0, 0);
            }
            __syncthreads();
        }

        // ---- finalize: l reduce across the 16 lanes sharing each row ----
        float inv[4];
        #pragma unroll
        for (int e = 0; e < 4; ++e) {
            float lt = l_acc[e];
            #pragma unroll
            for (int off = 1; off < 16; off <<= 1) lt += __shfl_xor(lt, off);
            inv[e] = cn / lt;
        }

        // ---- combine terms via LDS (term1 writes, term0 adds), then copy out ----
        if (n_term) {
            #pragma unroll
            for (int d = 0; d < 16; ++d)
                #pragma unroll
                for (int e = 0; e < 4; ++e)
                    OlP[(qh * 16 + quad * 4 + e) * OROWSTR + d * 16 + l15] = o[d][e] * inv[e];
        }
        __syncthreads();
        if (!n_term) {
            #pragma unroll
            for (int d = 0; d < 16; ++d)
                #pragma unroll
                for (int e = 0; e < 4; ++e)
                    OlP[(qh * 16 + quad * 4 + e) * OROWSTR + d * 16 + l15] += o[d][e] * inv[e];
        }
        __syncthreads();
        #pragma unroll
        for (int rep = 0; rep < 8; ++rep) {
            int idx = t + rep * 256;          // 32 rows x 64 float4
            int row = idx >> 6, c4 = idx & 63;
            float4 val = *(const float4*)&OlP[row * OROWSTR + c4 * 4];
            *(float4*)&outp[((size_t)(b * T_DIM + q0 + row)) * VD + c4 * 4] = val;
        }
        __syncthreads();
    }
}

extern "C" void kernel_launch(void* const* d_in, const int* in_sizes, int n_in,
                              void* d_out, int out_size, void* d_ws, size_t ws_size,
                              hipStream_t stream) {
    const float* x  = (const float*)d_in[0];
    const float* Wq = (const float*)d_in[1];
    const float* Wk = (const float*)d_in[2];
    const float* Wv = (const float*)d_in[3];
    const float* lq = (const float*)d_in[4];
    const float* lk = (const float*)d_in[5];
    const int* lidx = (const int*)d_in[6];

    unsigned short* qb  = (unsigned short*)d_ws;      // [2][8][2048][128] bf16
    unsigned short* kb  = qb + 2 * (size_t)QK_ELEMS;  // [2][8][2048][128] bf16
    unsigned short* vTb = kb + 2 * (size_t)QK_ELEMS;  // [8][256][2048] bf16
    float* lamb = (float*)(vTb + 2 * (size_t)QK_ELEMS);
    (void)ws_size; (void)in_sizes; (void)n_in; (void)out_size;

    lam_kernel<<<dim3(1), dim3(64), 0, stream>>>(lq, lk, lidx, lamb);
    proj_kernel<<<dim3(128, 6), dim3(256), 0, stream>>>(x, Wq, Wk, Wv, qb, kb, vTb);
    attn_kernel<<<dim3(256), dim3(256), 0, stream>>>(qb, kb, vTb, lamb, (float*)d_out);
}

// Round 3
// 250.661 us; speedup vs baseline: 5.3173x; 1.9506x over previous
//
#include <hip/hip_runtime.h>
#include <math.h>

// Problem constants
#define B_DIM 8
#define T_DIM 2048
#define C_DIM 1024
#define HS_DIM 128
#define VD 256
#define M_DIM (B_DIM * T_DIM)            // 16384 rows
#define QK_ELEMS (M_DIM * HS_DIM)        // 2,097,152 elems per (q|k) term
#define SCALE 0.088388347648318447f      // 1/sqrt(128)
#define LOG_THETA 9.210340371976184f     // ln(10000)

// workspace layout (ushort units)
#define QB_OFF   0u
#define KB_OFF   4194304u
#define VT_OFF   8388608u
#define WT_OFF   12582912u
#define XBH_OFF  13369344u               // x-bf16 rows 8192..16383
#define LAM_OFF  21757952u
#define XSPLIT_ELEMS 8388608u            // rows 0..8191 of x-bf16 live in d_out

typedef short s8v  __attribute__((ext_vector_type(8)));   // 8 bf16 (4 VGPRs)
typedef float f32x4 __attribute__((ext_vector_type(4)));

// ---------- helpers ----------
__device__ __forceinline__ unsigned int bf16_rne(float f) {
    unsigned int u = __float_as_uint(f);
    return (u + 0x7fffu + ((u >> 16) & 1u)) >> 16;
}
__device__ __forceinline__ unsigned int pack_bf2(float lo, float hi) {
    return bf16_rne(lo) | (bf16_rne(hi) << 16);
}
__device__ __forceinline__ void async_cp16(const unsigned short* g, unsigned short* l) {
    __builtin_amdgcn_global_load_lds(
        (const __attribute__((address_space(1))) unsigned int*)g,
        (__attribute__((address_space(3))) unsigned int*)l, 16, 0, 0);
}

// ---------- kernel 1: lambda coefficients ----------
__global__ void lam_kernel(const float* __restrict__ lq, const float* __restrict__ lk,
                           const int* __restrict__ lidx, float* __restrict__ lam_out) {
    int t = threadIdx.x; // 64 threads = 1 wave
    float s0 = expf(lq[t] * lk[t]) + expf(lq[t + 64] * lk[t + 64]);
    float s1 = expf(lq[128 + t] * lk[128 + t]) + expf(lq[192 + t] * lk[192 + t]);
    #pragma unroll
    for (int off = 32; off > 0; off >>= 1) {
        s0 += __shfl_down(s0, off);
        s1 += __shfl_down(s1, off);
    }
    if (t == 0) {
        float e0 = s0 * (1.0f / 128.0f);
        float e1 = s1 * (1.0f / 128.0f);
        float li = 0.8f - 0.6f * expf(-0.3f * ((float)lidx[0] - 1.0f));
        lam_out[0] = e0 + li;            // +lam0
        lam_out[1] = -(e1 - e0 + li);    // -lam1
    }
}

// ---------- kernel 2a: cast x -> bf16 (split across d_out scratch + ws) ----------
__global__ __launch_bounds__(256) void cast_x_kernel(const float* __restrict__ x,
                                                     unsigned short* __restrict__ lo,
                                                     unsigned short* __restrict__ hi) {
    const size_t i8 = ((size_t)blockIdx.x * 256 + threadIdx.x) * 8;
    float4 a = *(const float4*)(x + i8);
    float4 b = *(const float4*)(x + i8 + 4);
    uint4 u;
    u.x = pack_bf2(a.x, a.y); u.y = pack_bf2(a.z, a.w);
    u.z = pack_bf2(b.x, b.y); u.w = pack_bf2(b.z, b.w);
    unsigned short* dst = (i8 < XSPLIT_ELEMS) ? (lo + i8) : (hi + (i8 - XSPLIT_ELEMS));
    *(uint4*)dst = u;
}

// ---------- kernel 2b: build Wt[768][1024] bf16 (transposed, concatenated) ----
// rows 0-127 Wq[0], 128-255 Wq[1], 256-383 Wk[0], 384-511 Wk[1], 512-767 Wv
__global__ __launch_bounds__(256) void cast_wt_kernel(
    const float* __restrict__ Wq, const float* __restrict__ Wk,
    const float* __restrict__ Wv, unsigned short* __restrict__ wt) {
    __shared__ float tile[32][33];
    const int t = threadIdx.x;
    const int n0 = blockIdx.x * 32;
    const int k0 = blockIdx.y * 32;
    const int seg = n0 >> 7;
    const int nl = t & 31;
    const int ng = n0 + nl;
    const float* src; int ld;
    if (seg < 2)      { src = Wq + (size_t)seg * (C_DIM * HS_DIM) + (ng & 127); ld = 128; }
    else if (seg < 4) { src = Wk + (size_t)(seg - 2) * (C_DIM * HS_DIM) + (ng & 127); ld = 128; }
    else              { src = Wv + (ng - 512); ld = 256; }
    #pragma unroll
    for (int rep = 0; rep < 4; ++rep) {
        int kl = (t >> 5) + rep * 8;
        tile[kl][nl] = src[(size_t)(k0 + kl) * ld];
    }
    __syncthreads();
    unsigned int* wt32 = (unsigned int*)wt;
    #pragma unroll
    for (int rep = 0; rep < 2; ++rep) {
        int nl2 = (t >> 4) + rep * 16;
        int k2 = (t & 15) * 2;
        unsigned int u = pack_bf2(tile[k2][nl2], tile[k2 + 1][nl2]);
        wt32[((size_t)(n0 + nl2) * 1024 + k0 + k2) >> 1] = u;
    }
}

// ---------- kernel 2c: bf16 MFMA GEMM + RoPE / V-transpose epilogue ----------
// C[16384][768] = xb[16384][1024] @ Wt[768][1024]^T ; 128x128 tiles, BK=32,
// 4 waves x (4x4) 16x16x32 MFMAs, global_load_lds width-16 staging (m97).
__global__ __launch_bounds__(256) void gemm_kernel(
    const unsigned short* __restrict__ xlo, const unsigned short* __restrict__ xhi,
    const unsigned short* __restrict__ wt,
    unsigned short* __restrict__ qo, unsigned short* __restrict__ ko,
    unsigned short* __restrict__ vo) {
    __shared__ unsigned short As[128 * 32];   // 8 KB, row-major [128][32]
    __shared__ unsigned short Bs[128 * 32];   // 8 KB, row-major [128][32]

    const int t = threadIdx.x;
    const int wv = t >> 6, lane = t & 63;
    const int quad = lane >> 4, l15 = lane & 15;
    const int m0 = blockIdx.x * 128;
    const int n0 = blockIdx.y * 128;
    const int wr = wv >> 1, wc = wv & 1;

    const unsigned short* xbase = (m0 < 8192)
        ? (xlo + (size_t)m0 * C_DIM) : (xhi + (size_t)(m0 - 8192) * C_DIM);

    f32x4 acc[4][4];
    #pragma unroll
    for (int i = 0; i < 4; ++i)
        #pragma unroll
        for (int j = 0; j < 4; ++j) acc[i][j] = (f32x4){0.f, 0.f, 0.f, 0.f};

    // staging: chunk c = wv*2+j covers rows c*16..c*16+15; lane -> row c*16+(lane>>2),
    // k-offset (lane&3)*8; LDS dst = base + c*1024B + lane*16B (contiguous, as required)
    const int srow = lane >> 2;
    const int skof = (lane & 3) * 8;

    for (int k0 = 0; k0 < C_DIM; k0 += 32) {
        #pragma unroll
        for (int j = 0; j < 2; ++j) {
            const int c = wv * 2 + j;
            async_cp16(xbase + (size_t)(c * 16 + srow) * C_DIM + k0 + skof, As + c * 512);
        }
        #pragma unroll
        for (int j = 0; j < 2; ++j) {
            const int c = wv * 2 + j;
            async_cp16(wt + (size_t)(n0 + c * 16 + srow) * C_DIM + k0 + skof, Bs + c * 512);
        }
        __syncthreads();
        s8v af[4], bf[4];
        #pragma unroll
        for (int i = 0; i < 4; ++i)
            af[i] = *(const s8v*)&As[(wr * 64 + i * 16 + l15) * 32 + quad * 8];
        #pragma unroll
        for (int j = 0; j < 4; ++j)
            bf[j] = *(const s8v*)&Bs[(wc * 64 + j * 16 + l15) * 32 + quad * 8];
        #pragma unroll
        for (int i = 0; i < 4; ++i)
            #pragma unroll
            for (int j = 0; j < 4; ++j)
                acc[i][j] = __builtin_amdgcn_mfma_f32_16x16x32_bf16(af[i], bf[j], acc[i][j], 0, 0, 0);
        __syncthreads();
    }

    // epilogue — C/D layout: row = quad*4+e, col = l15 (within each 16x16 tile)
    const int seg = n0 >> 7;   // 0..5
    if (seg < 4) {
        // Q/K: RoPE (pairs are adjacent lanes) then bf16 row-major [term][m][128]
        unsigned short* dstbuf = ((seg < 2) ? qo : ko) + (size_t)(seg & 1) * QK_ELEMS;
        float freqj[4];
        #pragma unroll
        for (int j = 0; j < 4; ++j) {
            const int d = wc * 64 + j * 16 + l15;
            freqj[j] = __expf((float)(d >> 1) * (-LOG_THETA / 64.f));
        }
        const int odd = lane & 1;
        #pragma unroll
        for (int i = 0; i < 4; ++i) {
            #pragma unroll
            for (int e = 0; e < 4; ++e) {
                const int m = m0 + wr * 64 + i * 16 + quad * 4 + e;
                const float trow = (float)(m & (T_DIM - 1));
                unsigned int* p32 = (unsigned int*)(dstbuf + (size_t)m * HS_DIM);
                #pragma unroll
                for (int j = 0; j < 4; ++j) {
                    const int d = wc * 64 + j * 16 + l15;
                    const float val = acc[i][j][e];
                    const float other = __shfl_xor(val, 1);
                    float sn_, cs_;
                    __sincosf(trow * freqj[j], &sn_, &cs_);
                    // even d: xr*cos - xi*sin ; odd d: xi*cos + xr*sin
                    const float out = val * cs_ + (odd ? other * sn_ : -other * sn_);
                    const float out2 = __shfl_xor(out, 1);
                    if (!odd) p32[d >> 1] = pack_bf2(out, out2);
                }
            }
        }
    } else {
        // V: bf16 transposed vT[b][256][2048]; lane holds 4 consecutive tokens per (i,j)
        const int bq = m0 >> 11;
        const int tbase = m0 & (T_DIM - 1);
        unsigned int* vT32 = (unsigned int*)vo;
        #pragma unroll
        for (int j = 0; j < 4; ++j) {
            const int d = (seg - 4) * 128 + wc * 64 + j * 16 + l15;
            const size_t rowbase = (size_t)(bq * VD + d) * (T_DIM / 2); // u32 units
            #pragma unroll
            for (int i = 0; i < 4; ++i) {
                const int tok = tbase + wr * 64 + i * 16 + quad * 4;
                uint2 u;
                u.x = pack_bf2(acc[i][j][0], acc[i][j][1]);
                u.y = pack_bf2(acc[i][j][2], acc[i][j][3]);
                *(uint2*)&vT32[rowbase + (tok >> 1)] = u;
            }
        }
    }
}

// ---------- kernel 3: dual-term causal attention, bf16 MFMA (unchanged) ----------
#define KROWSTR 136   // K LDS row stride (bf16), +8 pad
#define VROWSTR 40    // Vt LDS row stride
#define PROWSTR 40    // P LDS row stride
#define OROWSTR 268   // O LDS row stride (fp32)
#define SM_K_OFF 0
#define SM_V_OFF 17408
#define SM_P_OFF 37888
#define SM_TOTAL 43008

__global__ __launch_bounds__(256) void attn_kernel(
    const unsigned short* __restrict__ qg, const unsigned short* __restrict__ kg,
    const unsigned short* __restrict__ vg, const float* __restrict__ lam,
    float* __restrict__ outp) {
    __shared__ __align__(16) unsigned char smem[SM_TOTAL];
    unsigned short* KsP = (unsigned short*)(smem + SM_K_OFF);  // [2][32][136]
    unsigned short* VtP = (unsigned short*)(smem + SM_V_OFF);  // [256][40]
    unsigned short* PsP = (unsigned short*)(smem + SM_P_OFF);  // [4][16][40]
    float* OlP = (float*)smem;                                 // [2][16][268] overlays K+V

    const int t = threadIdx.x;
    const int id = blockIdx.x;
    const int b = id & 7;
    const int qt = id >> 3;        // 0..31
    const int w = t >> 6;
    const int lane = t & 63;
    const int quad = lane >> 4;
    const int l15 = lane & 15;
    const int n_term = w & 1;
    const int qh = w >> 1;

    const float cn = lam[n_term];  // lam[1] already carries the minus sign

    #pragma unroll
    for (int sidx = 0; sidx < 2; ++sidx) {
        const int qte = sidx ? (63 - qt) : qt;
        const int q0 = qte * 32;
        const int nt = qte + 1;

        const unsigned short* qrow = qg
            + ((size_t)(n_term * B_DIM + b) * T_DIM + q0 + 16 * qh + l15) * HS_DIM;
        s8v qa[4];
        #pragma unroll
        for (int kk = 0; kk < 4; ++kk)
            qa[kk] = *(const s8v*)(qrow + kk * 32 + quad * 8);

        f32x4 o[16];
        #pragma unroll
        for (int d = 0; d < 16; ++d) o[d] = (f32x4){0.f, 0.f, 0.f, 0.f};
        float l_acc[4] = {0.f, 0.f, 0.f, 0.f};

        for (int it = 0; it < nt; ++it) {
            const int s0 = it * 32;
            #pragma unroll
            for (int rep = 0; rep < 4; ++rep) {
                int idx = t + rep * 256;          // 0..1023 uint4s
                int n = idx >> 9, rem = idx & 511;
                int r = rem >> 4, seg = rem & 15;
                const uint4 g = *(const uint4*)(kg
                    + ((size_t)(n * B_DIM + b) * T_DIM + s0 + r) * HS_DIM + seg * 8);
                *(uint4*)&KsP[(n * 32 + r) * KROWSTR + seg * 8] = g;
            }
            #pragma unroll
            for (int rep = 0; rep < 4; ++rep) {
                int idx = t + rep * 256;          // 0..1023 uint4s
                int row = idx >> 2, seg = idx & 3;
                const uint4 g = *(const uint4*)(vg
                    + ((size_t)(b * VD + row) * T_DIM + s0) + seg * 8);
                *(uint4*)&VtP[row * VROWSTR + seg * 8] = g;
            }
            __syncthreads();

            #pragma unroll
            for (int ks = 0; ks < 2; ++ks) {
                f32x4 sc = (f32x4){0.f, 0.f, 0.f, 0.f};
                #pragma unroll
                for (int kk = 0; kk < 4; ++kk) {
                    s8v kf = *(const s8v*)&KsP[(n_term * 32 + ks * 16 + l15) * KROWSTR
                                               + kk * 32 + quad * 8];
                    sc = __builtin_amdgcn_mfma_f32_16x16x32_bf16(qa[kk], kf, sc, 0, 0, 0);
                }
                const int key = s0 + ks * 16 + l15;
                #pragma unroll
                for (int e = 0; e < 4; ++e) {
                    const int qrow_g = q0 + 16 * qh + quad * 4 + e;
                    const float p = (key <= qrow_g) ? __expf(sc[e] * SCALE) : 0.f;
                    l_acc[e] += p;
                    PsP[(w * 16 + quad * 4 + e) * PROWSTR + ks * 16 + l15] =
                        (unsigned short)bf16_rne(p);
                }
            }
            asm volatile("" ::: "memory");

            const s8v pa = *(const s8v*)&PsP[(w * 16 + l15) * PROWSTR + quad * 8];
            #pragma unroll
            for (int d = 0; d < 16; ++d) {
                s8v vb = *(const s8v*)&VtP[(d * 16 + l15) * VROWSTR + quad * 8];
                o[d] = __builtin_amdgcn_mfma_f32_16x16x32_bf16(pa, vb, o[d], 0, 0, 0);
            }
            __syncthreads();
        }

        float inv[4];
        #pragma unroll
        for (int e = 0; e < 4; ++e) {
            float lt = l_acc[e];
            #pragma unroll
            for (int off = 1; off < 16; off <<= 1) lt += __shfl_xor(lt, off);
            inv[e] = cn / lt;
        }

        if (n_term) {
            #pragma unroll
            for (int d = 0; d < 16; ++d)
                #pragma unroll
                for (int e = 0; e < 4; ++e)
                    OlP[(qh * 16 + quad * 4 + e) * OROWSTR + d * 16 + l15] = o[d][e] * inv[e];
        }
        __syncthreads();
        if (!n_term) {
            #pragma unroll
            for (int d = 0; d < 16; ++d)
                #pragma unroll
                for (int e = 0; e < 4; ++e)
                    OlP[(qh * 16 + quad * 4 + e) * OROWSTR + d * 16 + l15] += o[d][e] * inv[e];
        }
        __syncthreads();
        #pragma unroll
        for (int rep = 0; rep < 8; ++rep) {
            int idx = t + rep * 256;          // 32 rows x 64 float4
            int row = idx >> 6, c4 = idx & 63;
            float4 val = *(const float4*)&OlP[row * OROWSTR + c4 * 4];
            *(float4*)&outp[((size_t)(b * T_DIM + q0 + row)) * VD + c4 * 4] = val;
        }
        __syncthreads();
    }
}

extern "C" void kernel_launch(void* const* d_in, const int* in_sizes, int n_in,
                              void* d_out, int out_size, void* d_ws, size_t ws_size,
                              hipStream_t stream) {
    const float* x  = (const float*)d_in[0];
    const float* Wq = (const float*)d_in[1];
    const float* Wk = (const float*)d_in[2];
    const float* Wv = (const float*)d_in[3];
    const float* lq = (const float*)d_in[4];
    const float* lk = (const float*)d_in[5];
    const int* lidx = (const int*)d_in[6];

    unsigned short* ws = (unsigned short*)d_ws;
    unsigned short* qb   = ws + QB_OFF;    // [2][8][2048][128] bf16
    unsigned short* kb   = ws + KB_OFF;    // [2][8][2048][128] bf16
    unsigned short* vTb  = ws + VT_OFF;    // [8][256][2048] bf16
    unsigned short* wtb  = ws + WT_OFF;    // [768][1024] bf16
    unsigned short* xbhi = ws + XBH_OFF;   // x-bf16 rows 8192..16383
    float* lamb = (float*)(ws + LAM_OFF);
    unsigned short* xblo = (unsigned short*)d_out;  // x-bf16 rows 0..8191 (scratch;
                                                    // attn fully overwrites d_out later)
    (void)ws_size; (void)in_sizes; (void)n_in; (void)out_size;

    lam_kernel<<<dim3(1), dim3(64), 0, stream>>>(lq, lk, lidx, lamb);
    cast_x_kernel<<<dim3(8192), dim3(256), 0, stream>>>(x, xblo, xbhi);
    cast_wt_kernel<<<dim3(24, 32), dim3(256), 0, stream>>>(Wq, Wk, Wv, wtb);
    gemm_kernel<<<dim3(128, 6), dim3(256), 0, stream>>>(xblo, xbhi, wtb, qb, kb, vTb);
    attn_kernel<<<dim3(256), dim3(256), 0, stream>>>(qb, kb, vTb, lamb, (float*)d_out);
}

// Round 5
// 231.503 us; speedup vs baseline: 5.7573x; 1.0828x over previous
//
#include <hip/hip_runtime.h>
#include <math.h>

// Problem constants
#define B_DIM 8
#define T_DIM 2048
#define C_DIM 1024
#define HS_DIM 128
#define VD 256
#define M_DIM (B_DIM * T_DIM)            // 16384 rows
#define QK_ELEMS (M_DIM * HS_DIM)        // 2,097,152 elems per (q|k) term
#define SCALE 0.088388347648318447f      // 1/sqrt(128)
#define LOG_THETA 9.210340371976184f     // ln(10000)

// workspace layout (ushort units)
#define QB_OFF   0u
#define KB_OFF   4194304u
#define VT_OFF   8388608u
#define WT_OFF   12582912u
#define XBH_OFF  13369344u               // x-bf16 rows 8192..16383
#define LAM_OFF  21757952u
#define XSPLIT_ELEMS 8388608u            // rows 0..8191 of x-bf16 live in d_out

typedef short s8v   __attribute__((ext_vector_type(8)));   // 8 bf16 (4 VGPRs)
typedef float f32x4 __attribute__((ext_vector_type(4)));
typedef float f32x16 __attribute__((ext_vector_type(16)));

// ---------- helpers ----------
__device__ __forceinline__ unsigned int bf16_rne(float f) {
    unsigned int u = __float_as_uint(f);
    return (u + 0x7fffu + ((u >> 16) & 1u)) >> 16;
}
__device__ __forceinline__ unsigned int pack_bf2(float lo, float hi) {
    return bf16_rne(lo) | (bf16_rne(hi) << 16);
}
__device__ __forceinline__ void async_cp16(const unsigned short* g, unsigned short* l) {
    __builtin_amdgcn_global_load_lds(
        (const __attribute__((address_space(1))) unsigned int*)g,
        (__attribute__((address_space(3))) unsigned int*)l, 16, 0, 0);
}

// ---------- kernel 1: lambda coefficients ----------
__global__ void lam_kernel(const float* __restrict__ lq, const float* __restrict__ lk,
                           const int* __restrict__ lidx, float* __restrict__ lam_out) {
    int t = threadIdx.x; // 64 threads = 1 wave
    float s0 = expf(lq[t] * lk[t]) + expf(lq[t + 64] * lk[t + 64]);
    float s1 = expf(lq[128 + t] * lk[128 + t]) + expf(lq[192 + t] * lk[192 + t]);
    #pragma unroll
    for (int off = 32; off > 0; off >>= 1) {
        s0 += __shfl_down(s0, off);
        s1 += __shfl_down(s1, off);
    }
    if (t == 0) {
        float e0 = s0 * (1.0f / 128.0f);
        float e1 = s1 * (1.0f / 128.0f);
        float li = 0.8f - 0.6f * expf(-0.3f * ((float)lidx[0] - 1.0f));
        lam_out[0] = e0 + li;            // +lam0
        lam_out[1] = -(e1 - e0 + li);    // -lam1
    }
}

// ---------- kernel 2a: cast x -> bf16 (split across d_out scratch + ws) ----------
__global__ __launch_bounds__(256) void cast_x_kernel(const float* __restrict__ x,
                                                     unsigned short* __restrict__ lo,
                                                     unsigned short* __restrict__ hi) {
    const size_t i8 = ((size_t)blockIdx.x * 256 + threadIdx.x) * 8;
    float4 a = *(const float4*)(x + i8);
    float4 b = *(const float4*)(x + i8 + 4);
    uint4 u;
    u.x = pack_bf2(a.x, a.y); u.y = pack_bf2(a.z, a.w);
    u.z = pack_bf2(b.x, b.y); u.w = pack_bf2(b.z, b.w);
    unsigned short* dst = (i8 < XSPLIT_ELEMS) ? (lo + i8) : (hi + (i8 - XSPLIT_ELEMS));
    *(uint4*)dst = u;
}

// ---------- kernel 2b: build Wt[768][1024] bf16 (transposed, concatenated) ----
__global__ __launch_bounds__(256) void cast_wt_kernel(
    const float* __restrict__ Wq, const float* __restrict__ Wk,
    const float* __restrict__ Wv, unsigned short* __restrict__ wt) {
    __shared__ float tile[32][33];
    const int t = threadIdx.x;
    const int n0 = blockIdx.x * 32;
    const int k0 = blockIdx.y * 32;
    const int seg = n0 >> 7;
    const int nl = t & 31;
    const int ng = n0 + nl;
    const float* src; int ld;
    if (seg < 2)      { src = Wq + (size_t)seg * (C_DIM * HS_DIM) + (ng & 127); ld = 128; }
    else if (seg < 4) { src = Wk + (size_t)(seg - 2) * (C_DIM * HS_DIM) + (ng & 127); ld = 128; }
    else              { src = Wv + (ng - 512); ld = 256; }
    #pragma unroll
    for (int rep = 0; rep < 4; ++rep) {
        int kl = (t >> 5) + rep * 8;
        tile[kl][nl] = src[(size_t)(k0 + kl) * ld];
    }
    __syncthreads();
    unsigned int* wt32 = (unsigned int*)wt;
    #pragma unroll
    for (int rep = 0; rep < 2; ++rep) {
        int nl2 = (t >> 4) + rep * 16;
        int k2 = (t & 15) * 2;
        unsigned int u = pack_bf2(tile[k2][nl2], tile[k2 + 1][nl2]);
        wt32[((size_t)(n0 + nl2) * 1024 + k0 + k2) >> 1] = u;
    }
}

// ---------- kernel 2c: bf16 MFMA GEMM + RoPE / V-transpose epilogue ----------
__global__ __launch_bounds__(256) void gemm_kernel(
    const unsigned short* __restrict__ xlo, const unsigned short* __restrict__ xhi,
    const unsigned short* __restrict__ wt,
    unsigned short* __restrict__ qo, unsigned short* __restrict__ ko,
    unsigned short* __restrict__ vo) {
    __shared__ unsigned short As[128 * 32];   // 8 KB, row-major [128][32]
    __shared__ unsigned short Bs[128 * 32];   // 8 KB, row-major [128][32]

    const int t = threadIdx.x;
    const int wv = t >> 6, lane = t & 63;
    const int quad = lane >> 4, l15 = lane & 15;
    const int m0 = blockIdx.x * 128;
    const int n0 = blockIdx.y * 128;
    const int wr = wv >> 1, wc = wv & 1;

    const unsigned short* xbase = (m0 < 8192)
        ? (xlo + (size_t)m0 * C_DIM) : (xhi + (size_t)(m0 - 8192) * C_DIM);

    f32x4 acc[4][4];
    #pragma unroll
    for (int i = 0; i < 4; ++i)
        #pragma unroll
        for (int j = 0; j < 4; ++j) acc[i][j] = (f32x4){0.f, 0.f, 0.f, 0.f};

    const int srow = lane >> 2;
    const int skof = (lane & 3) * 8;

    for (int k0 = 0; k0 < C_DIM; k0 += 32) {
        #pragma unroll
        for (int j = 0; j < 2; ++j) {
            const int c = wv * 2 + j;
            async_cp16(xbase + (size_t)(c * 16 + srow) * C_DIM + k0 + skof, As + c * 512);
        }
        #pragma unroll
        for (int j = 0; j < 2; ++j) {
            const int c = wv * 2 + j;
            async_cp16(wt + (size_t)(n0 + c * 16 + srow) * C_DIM + k0 + skof, Bs + c * 512);
        }
        __syncthreads();
        s8v af[4], bf[4];
        #pragma unroll
        for (int i = 0; i < 4; ++i)
            af[i] = *(const s8v*)&As[(wr * 64 + i * 16 + l15) * 32 + quad * 8];
        #pragma unroll
        for (int j = 0; j < 4; ++j)
            bf[j] = *(const s8v*)&Bs[(wc * 64 + j * 16 + l15) * 32 + quad * 8];
        #pragma unroll
        for (int i = 0; i < 4; ++i)
            #pragma unroll
            for (int j = 0; j < 4; ++j)
                acc[i][j] = __builtin_amdgcn_mfma_f32_16x16x32_bf16(af[i], bf[j], acc[i][j], 0, 0, 0);
        __syncthreads();
    }

    const int seg = n0 >> 7;   // 0..5
    if (seg < 4) {
        unsigned short* dstbuf = ((seg < 2) ? qo : ko) + (size_t)(seg & 1) * QK_ELEMS;
        float freqj[4];
        #pragma unroll
        for (int j = 0; j < 4; ++j) {
            const int d = wc * 64 + j * 16 + l15;
            freqj[j] = __expf((float)(d >> 1) * (-LOG_THETA / 64.f));
        }
        const int odd = lane & 1;
        #pragma unroll
        for (int i = 0; i < 4; ++i) {
            #pragma unroll
            for (int e = 0; e < 4; ++e) {
                const int m = m0 + wr * 64 + i * 16 + quad * 4 + e;
                const float trow = (float)(m & (T_DIM - 1));
                unsigned int* p32 = (unsigned int*)(dstbuf + (size_t)m * HS_DIM);
                #pragma unroll
                for (int j = 0; j < 4; ++j) {
                    const int d = wc * 64 + j * 16 + l15;
                    const float val = acc[i][j][e];
                    const float other = __shfl_xor(val, 1);
                    float sn_, cs_;
                    __sincosf(trow * freqj[j], &sn_, &cs_);
                    const float out = val * cs_ + (odd ? other * sn_ : -other * sn_);
                    const float out2 = __shfl_xor(out, 1);
                    if (!odd) p32[d >> 1] = pack_bf2(out, out2);
                }
            }
        }
    } else {
        const int bq = m0 >> 11;
        const int tbase = m0 & (T_DIM - 1);
        unsigned int* vT32 = (unsigned int*)vo;
        #pragma unroll
        for (int j = 0; j < 4; ++j) {
            const int d = (seg - 4) * 128 + wc * 64 + j * 16 + l15;
            const size_t rowbase = (size_t)(bq * VD + d) * (T_DIM / 2); // u32 units
            #pragma unroll
            for (int i = 0; i < 4; ++i) {
                const int tok = tbase + wr * 64 + i * 16 + quad * 4;
                uint2 u;
                u.x = pack_bf2(acc[i][j][0], acc[i][j][1]);
                u.y = pack_bf2(acc[i][j][2], acc[i][j][3]);
                *(uint2*)&vT32[rowbase + (tok >> 1)] = u;
            }
        }
    }
}

// ---------- kernel 3: dual-term causal attention, 32x32 bf16 MFMA ----------
// Grid: 512 blocks = 64 strips x 8 batches; strip order pairs complementary
// heavy/light strips under linear CU assignment (id and id+256 sum to 63).
// Block: 256 threads / 4 waves; strip = 32 queries; K-tile = 64 keys.
// QK: wave=(term,khalf) -> S[32x32] via 8x mfma_32x32x16, Q in registers.
// PV: wave=(term,dhalf) -> O[32x128] via 16x mfma_32x32x16.
// Softmax denominator: per-wave k-half partials combined ACROSS kh waves via
// LDS (round-3 bug: intra-wave-only reduce gave l=0 -> inf -> NaN).
#define KSTR 136    // K LDS row stride (bf16)
#define VSTR 72     // Vt LDS row stride: 64 tok + 8 pad
#define PSTR 72     // P LDS row stride: 64 keys + 8 pad
#define OSTR 260    // O combine stride (fp32 words)
#define K_OFF 0
#define V_OFF 34816
#define P_OFF 71680
#define SM_TOTAL 80896

__global__ __launch_bounds__(256, 2) void attn_kernel(
    const unsigned short* __restrict__ qg, const unsigned short* __restrict__ kg,
    const unsigned short* __restrict__ vg, const float* __restrict__ lam,
    float* __restrict__ outp) {
    __shared__ __align__(16) unsigned char smem[SM_TOTAL];
    unsigned short* Ks = (unsigned short*)(smem + K_OFF);  // [2][64][136]
    unsigned short* Vt = (unsigned short*)(smem + V_OFF);  // [256][72]
    unsigned short* Ps = (unsigned short*)(smem + P_OFF);  // [2][32][72]
    float* Ol = (float*)smem;                              // [32][260] overlays K
    float* Lsum = (float*)(smem + P_OFF);                  // [2][2][32] overlays dead Ps

    const int t = threadIdx.x;
    const int id = blockIdx.x;
    const int b = id & 7;                  // batch -> XCD round-robin
    const int sidx = id >> 3;              // 0..63
    const int strip = (sidx < 32) ? (63 - sidx) : (sidx - 32); // complementary pairing
    const int q0 = strip * 32;
    const int nt = (strip >> 1) + 1;       // 64-key tiles

    const int w = t >> 6, lane = t & 63;
    const int l31 = lane & 31, lh = lane >> 5;
    const int term = w & 1;
    const int kh = w >> 1;                 // QK k-half / PV d-half

    const float cn = lam[term];            // lam[1] carries the minus sign

    // Q A-frags (32x32x16 layout: row=lane&31, k=lh*8+j), 8 k-steps in registers
    const unsigned short* qrow = qg
        + ((size_t)(term * B_DIM + b) * T_DIM + q0 + l31) * HS_DIM + lh * 8;
    s8v qa[8];
    #pragma unroll
    for (int ks = 0; ks < 8; ++ks)
        qa[ks] = *(const s8v*)(qrow + ks * 16);

    f32x16 o[4];
    #pragma unroll
    for (int dt = 0; dt < 4; ++dt)
        #pragma unroll
        for (int r = 0; r < 16; ++r) o[dt][r] = 0.f;
    float l_acc[16];
    #pragma unroll
    for (int r = 0; r < 16; ++r) l_acc[r] = 0.f;

    for (int it = 0; it < nt; ++it) {
        const int s0 = it * 64;
        // ---- stage K (2 terms x 64 keys x 128) ----
        #pragma unroll
        for (int rep = 0; rep < 8; ++rep) {
            int idx = t + rep * 256;       // 0..2047 uint4s
            int n = idx >> 10, rem = idx & 1023;
            int r = rem >> 4, seg = rem & 15;
            const uint4 g = *(const uint4*)(kg
                + ((size_t)(n * B_DIM + b) * T_DIM + s0 + r) * HS_DIM + seg * 8);
            *(uint4*)&Ks[(n * 64 + r) * KSTR + seg * 8] = g;
        }
        // ---- stage Vt (256 dims x 64 tokens) ----
        #pragma unroll
        for (int rep = 0; rep < 8; ++rep) {
            int idx = t + rep * 256;       // 0..2047 uint4s
            int d = idx >> 3, seg = idx & 7;
            const uint4 g = *(const uint4*)(vg
                + ((size_t)(b * VD + d) * T_DIM + s0) + seg * 8);
            *(uint4*)&Vt[d * VSTR + seg * 8] = g;
        }
        __syncthreads();

        // ---- QK: S[32q x 32k] for (term, khalf) ----
        f32x16 sc;
        #pragma unroll
        for (int r = 0; r < 16; ++r) sc[r] = 0.f;
        #pragma unroll
        for (int ks = 0; ks < 8; ++ks) {
            s8v kf = *(const s8v*)&Ks[(term * 64 + kh * 32 + l31) * KSTR
                                      + ks * 16 + lh * 8];
            sc = __builtin_amdgcn_mfma_f32_32x32x16_bf16(qa[ks], kf, sc, 0, 0, 0);
        }
        // exp + P write (C/D 32x32: col=l31, row=(r&3)+8*(r>>2)+4*lh)
        const int key = s0 + kh * 32 + l31;
        #pragma unroll
        for (int r = 0; r < 16; ++r) {
            const int row = (r & 3) + 8 * (r >> 2) + 4 * lh;
            const float p = (key <= q0 + row) ? __expf(sc[r] * SCALE) : 0.f;
            l_acc[r] += p;
            Ps[(term * 32 + row) * PSTR + kh * 32 + l31] = (unsigned short)bf16_rne(p);
        }
        __syncthreads();

        // ---- PV: O[32q x 128d] += P[32x64] @ V[64x128] for (term, dhalf) ----
        #pragma unroll
        for (int ks = 0; ks < 4; ++ks) {
            s8v pa = *(const s8v*)&Ps[(term * 32 + l31) * PSTR + ks * 16 + lh * 8];
            #pragma unroll
            for (int dt = 0; dt < 4; ++dt) {
                s8v vb = *(const s8v*)&Vt[(kh * 128 + dt * 32 + l31) * VSTR
                                          + ks * 16 + lh * 8];
                o[dt] = __builtin_amdgcn_mfma_f32_32x32x16_bf16(pa, vb, o[dt], 0, 0, 0);
            }
        }
        __syncthreads();
    }

    // ---- finalize l: intra-wave reduce over 32 key-columns, then combine
    //      the two kh-wave partials per (term,row) through LDS ----
    #pragma unroll
    for (int r = 0; r < 16; ++r) {
        float lt = l_acc[r];
        #pragma unroll
        for (int off = 1; off < 32; off <<= 1) lt += __shfl_xor(lt, off);
        if (l31 == 0) {
            const int row = (r & 3) + 8 * (r >> 2) + 4 * lh;
            Lsum[(term * 2 + kh) * 32 + row] = lt;
        }
    }
    __syncthreads();
    float inv[16];
    #pragma unroll
    for (int r = 0; r < 16; ++r) {
        const int row = (r & 3) + 8 * (r >> 2) + 4 * lh;
        inv[r] = cn / (Lsum[(term * 2 + 0) * 32 + row] + Lsum[(term * 2 + 1) * 32 + row]);
    }

    // ---- combine terms via LDS overlay on K region ----
    if (term) {
        #pragma unroll
        for (int dt = 0; dt < 4; ++dt)
            #pragma unroll
            for (int r = 0; r < 16; ++r) {
                const int row = (r & 3) + 8 * (r >> 2) + 4 * lh;
                Ol[row * OSTR + kh * 128 + dt * 32 + l31] = o[dt][r] * inv[r];
            }
    }
    __syncthreads();
    if (!term) {
        #pragma unroll
        for (int dt = 0; dt < 4; ++dt)
            #pragma unroll
            for (int r = 0; r < 16; ++r) {
                const int row = (r & 3) + 8 * (r >> 2) + 4 * lh;
                Ol[row * OSTR + kh * 128 + dt * 32 + l31] += o[dt][r] * inv[r];
            }
    }
    __syncthreads();
    #pragma unroll
    for (int rep = 0; rep < 8; ++rep) {
        int idx = t + rep * 256;           // 32 rows x 64 float4
        int row = idx >> 6, c4 = idx & 63;
        float4 val = *(const float4*)&Ol[row * OSTR + c4 * 4];
        *(float4*)&outp[((size_t)(b * T_DIM + q0 + row)) * VD + c4 * 4] = val;
    }
}

extern "C" void kernel_launch(void* const* d_in, const int* in_sizes, int n_in,
                              void* d_out, int out_size, void* d_ws, size_t ws_size,
                              hipStream_t stream) {
    const float* x  = (const float*)d_in[0];
    const float* Wq = (const float*)d_in[1];
    const float* Wk = (const float*)d_in[2];
    const float* Wv = (const float*)d_in[3];
    const float* lq = (const float*)d_in[4];
    const float* lk = (const float*)d_in[5];
    const int* lidx = (const int*)d_in[6];

    unsigned short* ws = (unsigned short*)d_ws;
    unsigned short* qb   = ws + QB_OFF;    // [2][8][2048][128] bf16
    unsigned short* kb   = ws + KB_OFF;    // [2][8][2048][128] bf16
    unsigned short* vTb  = ws + VT_OFF;    // [8][256][2048] bf16
    unsigned short* wtb  = ws + WT_OFF;    // [768][1024] bf16
    unsigned short* xbhi = ws + XBH_OFF;   // x-bf16 rows 8192..16383
    float* lamb = (float*)(ws + LAM_OFF);
    unsigned short* xblo = (unsigned short*)d_out;  // scratch; attn overwrites d_out
    (void)ws_size; (void)in_sizes; (void)n_in; (void)out_size;

    lam_kernel<<<dim3(1), dim3(64), 0, stream>>>(lq, lk, lidx, lamb);
    cast_x_kernel<<<dim3(8192), dim3(256), 0, stream>>>(x, xblo, xbhi);
    cast_wt_kernel<<<dim3(24, 32), dim3(256), 0, stream>>>(Wq, Wk, Wv, wtb);
    gemm_kernel<<<dim3(128, 6), dim3(256), 0, stream>>>(xblo, xbhi, wtb, qb, kb, vTb);
    attn_kernel<<<dim3(512), dim3(256), 0, stream>>>(qb, kb, vTb, lamb, (float*)d_out);
}